// Round 4
// baseline (399.321 us; speedup 1.0000x reference)
//
#include <hip/hip_runtime.h>
#include <hip/hip_bf16.h>

typedef __bf16 bf16;
typedef __bf16 bf16x8 __attribute__((ext_vector_type(8)));
typedef float  f32x4  __attribute__((ext_vector_type(4)));

// ---------------------------------------------------------------------------
// NNConv via shared-weight GEMM on rank-1 edge features:
//   msg[e] = Z[e] @ W' (+ bias fold),  Z[e][(j,i)] = he[e][j]*x[src][i]
// R4: edges are counting-sorted by dst in-call (hist -> scan -> scatter).
//   * edge streams are coalesced
//   * aggregation = wave-level segment scan over sorted 16-edge tiles,
//     ~2 atomicAdd instructions per tile instead of 16
//   * deg[] from the histogram replaces the cnt atomics
// Pooling: batch sorted -> per-graph block segment reduction, no atomics.
// ---------------------------------------------------------------------------

__global__ void hist_deg(const int* __restrict__ eidx, int* __restrict__ deg, int E)
{
    int e = blockIdx.x * blockDim.x + threadIdx.x;
    if (e < E) atomicAdd(&deg[eidx[E + e]], 1);
}

// Single-block exclusive scan of deg[N] -> cursor[N] (1024 thr x 49 items).
__global__ void scan_deg(const int* __restrict__ deg, int* __restrict__ cursor, int N)
{
    __shared__ int part[1024];
    const int t = threadIdx.x;
    const int CH = (N + 1023) >> 10;
    const int base = t * CH;
    int sum = 0;
    for (int k = 0; k < CH; ++k) {
        int i = base + k;
        if (i < N) sum += deg[i];
    }
    part[t] = sum;
    __syncthreads();
    for (int off = 1; off < 1024; off <<= 1) {
        int add = (t >= off) ? part[t - off] : 0;
        __syncthreads();
        part[t] += add;
        __syncthreads();
    }
    int run = part[t] - sum;   // exclusive prefix for this chunk
    for (int k = 0; k < CH; ++k) {
        int i = base + k;
        if (i < N) { cursor[i] = run; run += deg[i]; }
    }
}

__global__ void scatter_edges(const int* __restrict__ eidx, const float* __restrict__ ea,
                              int* __restrict__ cursor,
                              int* __restrict__ src_s, int* __restrict__ dst_s,
                              float* __restrict__ ea_s, int E)
{
    int e = blockIdx.x * blockDim.x + threadIdx.x;
    if (e >= E) return;
    int d = eidx[E + e];
    int p = atomicAdd(&cursor[d], 1);
    src_s[p] = eidx[e];
    dst_s[p] = d;
    ea_s[p]  = ea[e];
}

// Per-node: r1 = x@root1 + bias1
__global__ void node_pre1(const float* __restrict__ x,
                          const float* __restrict__ root1,
                          const float* __restrict__ bias1,
                          float* __restrict__ r1, int N)
{
    int t = blockIdx.x * blockDim.x + threadIdx.x;
    int v = t >> 4, o = t & 15;
    if (v >= N) return;
    float racc = 0.f;
#pragma unroll
    for (int i = 0; i < 8; ++i)
        racc += x[v * 8 + i] * root1[i * 16 + o];
    r1[v * 16 + o] = racc + bias1[o];
}

// Edge layer 1: sorted tiles, K=128 via 4x mfma + 1 bias-mfma, segment epilogue.
__global__ void edge_l1(const float* __restrict__ x,
                        const float* __restrict__ ea_s,
                        const int*   __restrict__ src_s, const int* __restrict__ dst_s,
                        const float* __restrict__ W_e1a, const float* __restrict__ b_e1a,
                        const float* __restrict__ W_e1b, const float* __restrict__ b_e1b,
                        float* __restrict__ agg, int ntiles)
{
    const int lane = threadIdx.x & 63;
    const int m = lane & 15;          // A row (edge) / B,C col (chan)
    const int q = lane >> 4;
    const int wave   = blockIdx.x * (blockDim.x >> 6) + (threadIdx.x >> 6);
    const int nwaves = gridDim.x * (blockDim.x >> 6);

    bf16x8 bfrag[4];
#pragma unroll
    for (int c = 0; c < 4; ++c)
#pragma unroll
        for (int t = 0; t < 8; ++t)
            bfrag[c][t] = (bf16)W_e1b[(t * 16 + m) * 16 + (c * 4 + q)];
    bf16x8 bfrag5 = {};
    if (q == 0)
#pragma unroll
        for (int t = 0; t < 8; ++t)
            bfrag5[t] = (bf16)b_e1b[t * 16 + m];

    for (int tile = wave; tile < ntiles; tile += nwaves) {
        int e = tile * 16 + m;
        int s = src_s[e];
        int d = dst_s[e];
        float t_ea = ea_s[e];

        float he[4];
#pragma unroll
        for (int c = 0; c < 4; ++c) {
            int j = c * 4 + q;
            float h = W_e1a[j] * t_ea + b_e1a[j];
            he[c] = h > 0.f ? h : 0.f;
        }

        const float4* xp = (const float4*)(x + (size_t)s * 8);
        float4 x0 = xp[0], x1 = xp[1];
        float xv[8] = {x0.x, x0.y, x0.z, x0.w, x1.x, x1.y, x1.z, x1.w};

        f32x4 acc = {0.f, 0.f, 0.f, 0.f};
#pragma unroll
        for (int c = 0; c < 4; ++c) {
            bf16x8 afrag;
#pragma unroll
            for (int t = 0; t < 8; ++t) afrag[t] = (bf16)(he[c] * xv[t]);
            acc = __builtin_amdgcn_mfma_f32_16x16x32_bf16(afrag, bfrag[c], acc, 0, 0, 0);
        }
        {   // bias contraction (quad 0 active)
            bf16x8 a5 = {};
            if (q == 0)
#pragma unroll
                for (int t = 0; t < 8; ++t) a5[t] = (bf16)xv[t];
            acc = __builtin_amdgcn_mfma_f32_16x16x32_bf16(a5, bfrag5, acc, 0, 0, 0);
        }

        // Segment epilogue: rows sorted by dst; run-length combine, atomic
        // once per run. All quads compute identical scans; quad 0 commits.
        int   run_d   = __shfl(d, 0, 64);
        float run_sum = 0.f;
#pragma unroll
        for (int r = 0; r < 16; ++r) {
            int   dr = __shfl(d, r, 64);                       // wave-uniform
            float vr = __shfl(acc[r & 3], ((r >> 2) << 4) + m, 64);
            if (dr != run_d) {
                if (q == 0) atomicAdd(&agg[(size_t)run_d * 16 + m], run_sum);
                run_sum = 0.f; run_d = dr;
            }
            run_sum += vr;
        }
        if (q == 0) atomicAdd(&agg[(size_t)run_d * 16 + m], run_sum);
    }
}

// Finalize layer 1 + r2 precompute (deg from histogram).
__global__ void node_fin1(const float* __restrict__ agg, const int* __restrict__ deg,
                          const float* __restrict__ r1,
                          const float* __restrict__ root2,
                          const float* __restrict__ bias2,
                          float* __restrict__ h1, float* __restrict__ r2, int N)
{
    int t = blockIdx.x * blockDim.x + threadIdx.x;
    int v = t >> 4, o = t & 15;
    if (v >= N) return;
    float c = (float)deg[v]; c = c > 1.f ? c : 1.f;
    float h = agg[v * 16 + o] / c + r1[v * 16 + o];
    h = h > 0.f ? h : 0.f;
    h1[v * 16 + o] = h;
    float racc = 0.f;
#pragma unroll
    for (int i = 0; i < 16; ++i)
        racc += __shfl(h, i, 16) * root2[i * 16 + o];
    r2[v * 16 + o] = racc + bias2[o];
}

// Edge layer 2: K=256 via 8x mfma + 1 bias-mfma, segment epilogue.
__global__ void edge_l2(const float* __restrict__ h1g,
                        const float* __restrict__ ea_s,
                        const int*   __restrict__ src_s, const int* __restrict__ dst_s,
                        const float* __restrict__ W_e2a, const float* __restrict__ b_e2a,
                        const float* __restrict__ W_e2b, const float* __restrict__ b_e2b,
                        float* __restrict__ agg, int ntiles)
{
    const int lane = threadIdx.x & 63;
    const int m = lane & 15;
    const int q = lane >> 4;
    const int qh = q >> 1;            // j = 2c + qh
    const int ql = q & 1;             // i = ql*8 + t
    const int wave   = blockIdx.x * (blockDim.x >> 6) + (threadIdx.x >> 6);
    const int nwaves = gridDim.x * (blockDim.x >> 6);

    bf16x8 bfrag[8];
#pragma unroll
    for (int c = 0; c < 8; ++c) {
        int j = c * 2 + qh;
#pragma unroll
        for (int t = 0; t < 8; ++t)
            bfrag[c][t] = (bf16)W_e2b[((ql * 8 + t) * 16 + m) * 16 + j];
    }
    bf16x8 bfrag5 = {};
    if (q < 2)
#pragma unroll
        for (int t = 0; t < 8; ++t)
            bfrag5[t] = (bf16)b_e2b[(q * 8 + t) * 16 + m];

    for (int tile = wave; tile < ntiles; tile += nwaves) {
        int e = tile * 16 + m;
        int s = src_s[e];
        int d = dst_s[e];
        float t_ea = ea_s[e];

        float he[8];
#pragma unroll
        for (int c = 0; c < 8; ++c) {
            int j = c * 2 + qh;
            float h = W_e2a[j] * t_ea + b_e2a[j];
            he[c] = h > 0.f ? h : 0.f;
        }

        const float4* hp = (const float4*)(h1g + (size_t)s * 16 + ql * 8);
        float4 h0 = hp[0], h1v = hp[1];
        float hv[8] = {h0.x, h0.y, h0.z, h0.w, h1v.x, h1v.y, h1v.z, h1v.w};

        f32x4 acc = {0.f, 0.f, 0.f, 0.f};
#pragma unroll
        for (int c = 0; c < 8; ++c) {
            bf16x8 afrag;
#pragma unroll
            for (int t = 0; t < 8; ++t) afrag[t] = (bf16)(he[c] * hv[t]);
            acc = __builtin_amdgcn_mfma_f32_16x16x32_bf16(afrag, bfrag[c], acc, 0, 0, 0);
        }
        {   // bias contraction (quads 0,1 hold h1[s][0..16))
            bf16x8 a5 = {};
            if (q < 2)
#pragma unroll
                for (int t = 0; t < 8; ++t) a5[t] = (bf16)hv[t];
            acc = __builtin_amdgcn_mfma_f32_16x16x32_bf16(a5, bfrag5, acc, 0, 0, 0);
        }

        int   run_d   = __shfl(d, 0, 64);
        float run_sum = 0.f;
#pragma unroll
        for (int r = 0; r < 16; ++r) {
            int   dr = __shfl(d, r, 64);
            float vr = __shfl(acc[r & 3], ((r >> 2) << 4) + m, 64);
            if (dr != run_d) {
                if (q == 0) atomicAdd(&agg[(size_t)run_d * 16 + m], run_sum);
                run_sum = 0.f; run_d = dr;
            }
            run_sum += vr;
        }
        if (q == 0) atomicAdd(&agg[(size_t)run_d * 16 + m], run_sum);
    }
}

// Finalize layer 2: pure streaming elementwise.
__global__ void node_fin2(const float* __restrict__ agg, const int* __restrict__ deg,
                          const float* __restrict__ r2, const int* __restrict__ batch,
                          float* __restrict__ out_h, float* __restrict__ out_b, int N)
{
    int t = blockIdx.x * blockDim.x + threadIdx.x;
    int v = t >> 4, o = t & 15;
    if (v >= N) return;
    float c = (float)deg[v]; c = c > 1.f ? c : 1.f;
    float h = agg[v * 16 + o] / c + r2[v * 16 + o];
    h = h > 0.f ? h : 0.f;
    out_h[v * 16 + o] = h;
    if (o == 0) out_b[v] = (float)batch[v];
}

// Global mean pool: one block per graph, binary-search range, LDS reduce.
__global__ void pool_seg(const float* __restrict__ h, const int* __restrict__ batch,
                         float* __restrict__ out_g, int N)
{
    const int b = blockIdx.x;
    int lo = 0, hi = N;
    while (lo < hi) { int mid = (lo + hi) >> 1; if (batch[mid] < b) lo = mid + 1; else hi = mid; }
    const int start = lo;
    hi = N;
    while (lo < hi) { int mid = (lo + hi) >> 1; if (batch[mid] < b + 1) lo = mid + 1; else hi = mid; }
    const int end = lo;

    const int ch = threadIdx.x & 15, grp = threadIdx.x >> 4;
    float acc = 0.f;
    for (int v = start + grp; v < end; v += 16)
        acc += h[(size_t)v * 16 + ch];

    __shared__ float red[256];
    red[threadIdx.x] = acc;
    __syncthreads();
#pragma unroll
    for (int s = 128; s >= 16; s >>= 1) {
        if (threadIdx.x < s) red[threadIdx.x] += red[threadIdx.x + s];
        __syncthreads();
    }
    if (threadIdx.x < 16) {
        float c = (float)(end - start); c = c > 1.f ? c : 1.f;
        out_g[b * 16 + threadIdx.x] = red[threadIdx.x] / c;
    }
}

extern "C" void kernel_launch(void* const* d_in, const int* in_sizes, int n_in,
                              void* d_out, int out_size, void* d_ws, size_t ws_size,
                              hipStream_t stream)
{
    const float* x     = (const float*)d_in[0];
    const float* ea    = (const float*)d_in[1];
    const float* W_e1a = (const float*)d_in[2];
    const float* b_e1a = (const float*)d_in[3];
    const float* W_e1b = (const float*)d_in[4];
    const float* b_e1b = (const float*)d_in[5];
    const float* root1 = (const float*)d_in[6];
    const float* bias1 = (const float*)d_in[7];
    const float* W_e2a = (const float*)d_in[8];
    const float* b_e2a = (const float*)d_in[9];
    const float* W_e2b = (const float*)d_in[10];
    const float* b_e2b = (const float*)d_in[11];
    const float* root2 = (const float*)d_in[12];
    const float* bias2 = (const float*)d_in[13];
    const int*   eidx  = (const int*)d_in[14];
    const int*   batch = (const int*)d_in[15];

    const int E  = in_sizes[1];       // 800000
    const int N  = in_sizes[15];      // 50000
    const int Bg = (out_size - N * 16 - N) / 16;   // 64

    char* ws = (char*)d_ws;
    size_t off = 0;
    int*   deg  = (int*)(ws + off);   off += (size_t)N * 4;
    float* agg1 = (float*)(ws + off); off += (size_t)N * 16 * 4;
    float* agg2 = (float*)(ws + off); off += (size_t)N * 16 * 4;
    size_t zero_bytes = off;
    int*   cursor = (int*)(ws + off); off += (size_t)N * 4;
    int*   src_s  = (int*)(ws + off); off += (size_t)E * 4;
    int*   dst_s  = (int*)(ws + off); off += (size_t)E * 4;
    float* ea_s   = (float*)(ws + off); off += (size_t)E * 4;
    float* h1 = (float*)(ws + off); off += (size_t)N * 16 * 4;
    float* r1 = (float*)(ws + off); off += (size_t)N * 16 * 4;
    float* r2 = (float*)(ws + off); off += (size_t)N * 16 * 4;

    hipMemsetAsync(d_ws, 0, zero_bytes, stream);

    int nodeBlocks = (N * 16 + 255) / 256;
    int edgeBlocks = (E + 255) / 256;
    int ntiles = E / 16;

    hist_deg<<<edgeBlocks, 256, 0, stream>>>(eidx, deg, E);
    scan_deg<<<1, 1024, 0, stream>>>(deg, cursor, N);
    scatter_edges<<<edgeBlocks, 256, 0, stream>>>(eidx, ea, cursor,
                                                  src_s, dst_s, ea_s, E);

    node_pre1<<<nodeBlocks, 256, 0, stream>>>(x, root1, bias1, r1, N);
    edge_l1<<<1024, 256, 0, stream>>>(x, ea_s, src_s, dst_s,
                                      W_e1a, b_e1a, W_e1b, b_e1b, agg1, ntiles);
    node_fin1<<<nodeBlocks, 256, 0, stream>>>(agg1, deg, r1, root2, bias2,
                                              h1, r2, N);
    edge_l2<<<1024, 256, 0, stream>>>(h1, ea_s, src_s, dst_s,
                                      W_e2a, b_e2a, W_e2b, b_e2b, agg2, ntiles);

    float* out_h = (float*)d_out;
    float* out_g = out_h + (size_t)N * 16;
    float* out_b = out_g + (size_t)Bg * 16;
    node_fin2<<<nodeBlocks, 256, 0, stream>>>(agg2, deg, r2, batch, out_h,
                                              out_b, N);
    pool_seg<<<Bg, 256, 0, stream>>>(out_h, batch, out_g, N);
}

// Round 5
// 348.560 us; speedup vs baseline: 1.1456x; 1.1456x over previous
//
#include <hip/hip_runtime.h>
#include <hip/hip_bf16.h>

typedef __bf16 bf16;
typedef __bf16 bf16x8 __attribute__((ext_vector_type(8)));
typedef float  f32x4  __attribute__((ext_vector_type(4)));

// ---------------------------------------------------------------------------
// NNConv via shared-weight GEMM on rank-1 edge features:
//   msg[e] = Z[e] @ W' (+ bias fold),  Z[e][(j,i)] = he[e][j]*x[src][i]
// Edges counting-sorted by dst in-call (hist -> multi-block scan -> scatter):
//   * edge streams coalesced; aggregation = wave segment scan, ~2 atomics/tile
//   * deg[] from the histogram replaces per-edge cnt atomics
// R5: scan is multi-block (R4's single-block scan was 97us on one CU).
// Pooling: batch sorted -> per-graph block segment reduction, no atomics.
// ---------------------------------------------------------------------------

__global__ void hist_deg(const int* __restrict__ eidx, int* __restrict__ deg, int E)
{
    int e = blockIdx.x * blockDim.x + threadIdx.x;
    if (e < E) atomicAdd(&deg[eidx[E + e]], 1);
}

// Stage 1: per-block (1024 elems) partial sums.
__global__ void partial_sums(const int* __restrict__ deg, int* __restrict__ bsum, int N)
{
    __shared__ int ts[256];
    const int t = threadIdx.x;
    const int base = blockIdx.x * 1024 + t * 4;
    int s = 0;
#pragma unroll
    for (int k = 0; k < 4; ++k)
        if (base + k < N) s += deg[base + k];
    ts[t] = s;
    __syncthreads();
    for (int st = 128; st >= 1; st >>= 1) {
        if (t < st) ts[t] += ts[t + st];
        __syncthreads();
    }
    if (t == 0) bsum[blockIdx.x] = ts[0];
}

// Stage 2: one wave scans the block sums in-place -> exclusive prefixes.
__global__ void scan_bsum(int* __restrict__ bsum, int nb)
{
    const int lane = threadIdx.x;   // 64 threads
    int base = 0;
    for (int start = 0; start < nb; start += 64) {
        int i = start + lane;
        int orig = (i < nb) ? bsum[i] : 0;
        int v = orig;
        for (int off = 1; off < 64; off <<= 1) {
            int u = __shfl_up(v, off, 64);
            if (lane >= off) v += u;
        }
        if (i < nb) bsum[i] = base + v - orig;   // exclusive
        base += __shfl(v, 63, 64);
    }
}

// Stage 3: per-block LDS scan + block offset -> cursor (exclusive prefix).
__global__ void emit_cursor(const int* __restrict__ deg, const int* __restrict__ bsum,
                            int* __restrict__ cursor, int N)
{
    __shared__ int ts[256];
    const int t = threadIdx.x;
    const int base = blockIdx.x * 1024 + t * 4;
    int v[4];
#pragma unroll
    for (int k = 0; k < 4; ++k)
        v[k] = (base + k < N) ? deg[base + k] : 0;
    int s = v[0] + v[1] + v[2] + v[3];
    ts[t] = s;
    __syncthreads();
    for (int off = 1; off < 256; off <<= 1) {
        int add = (t >= off) ? ts[t - off] : 0;
        __syncthreads();
        ts[t] += add;
        __syncthreads();
    }
    int excl = ts[t] - s + bsum[blockIdx.x];
    if (base + 0 < N) cursor[base + 0] = excl;
    if (base + 1 < N) cursor[base + 1] = excl + v[0];
    if (base + 2 < N) cursor[base + 2] = excl + v[0] + v[1];
    if (base + 3 < N) cursor[base + 3] = excl + v[0] + v[1] + v[2];
}

__global__ void scatter_edges(const int* __restrict__ eidx, const float* __restrict__ ea,
                              int* __restrict__ cursor,
                              int* __restrict__ src_s, int* __restrict__ dst_s,
                              float* __restrict__ ea_s, int E)
{
    int e = blockIdx.x * blockDim.x + threadIdx.x;
    if (e >= E) return;
    int d = eidx[E + e];
    int p = atomicAdd(&cursor[d], 1);
    src_s[p] = eidx[e];
    dst_s[p] = d;
    ea_s[p]  = ea[e];
}

// Per-node: r1 = x@root1 + bias1
__global__ void node_pre1(const float* __restrict__ x,
                          const float* __restrict__ root1,
                          const float* __restrict__ bias1,
                          float* __restrict__ r1, int N)
{
    int t = blockIdx.x * blockDim.x + threadIdx.x;
    int v = t >> 4, o = t & 15;
    if (v >= N) return;
    float racc = 0.f;
#pragma unroll
    for (int i = 0; i < 8; ++i)
        racc += x[v * 8 + i] * root1[i * 16 + o];
    r1[v * 16 + o] = racc + bias1[o];
}

// Edge layer 1: sorted tiles, K=128 via 4x mfma + 1 bias-mfma, segment epilogue.
__global__ void edge_l1(const float* __restrict__ x,
                        const float* __restrict__ ea_s,
                        const int*   __restrict__ src_s, const int* __restrict__ dst_s,
                        const float* __restrict__ W_e1a, const float* __restrict__ b_e1a,
                        const float* __restrict__ W_e1b, const float* __restrict__ b_e1b,
                        float* __restrict__ agg, int ntiles)
{
    const int lane = threadIdx.x & 63;
    const int m = lane & 15;          // A row (edge) / B,C col (chan)
    const int q = lane >> 4;
    const int wave   = blockIdx.x * (blockDim.x >> 6) + (threadIdx.x >> 6);
    const int nwaves = gridDim.x * (blockDim.x >> 6);

    bf16x8 bfrag[4];
#pragma unroll
    for (int c = 0; c < 4; ++c)
#pragma unroll
        for (int t = 0; t < 8; ++t)
            bfrag[c][t] = (bf16)W_e1b[(t * 16 + m) * 16 + (c * 4 + q)];
    bf16x8 bfrag5 = {};
    if (q == 0)
#pragma unroll
        for (int t = 0; t < 8; ++t)
            bfrag5[t] = (bf16)b_e1b[t * 16 + m];

    for (int tile = wave; tile < ntiles; tile += nwaves) {
        int e = tile * 16 + m;
        int s = src_s[e];
        int d = dst_s[e];
        float t_ea = ea_s[e];

        float he[4];
#pragma unroll
        for (int c = 0; c < 4; ++c) {
            int j = c * 4 + q;
            float h = W_e1a[j] * t_ea + b_e1a[j];
            he[c] = h > 0.f ? h : 0.f;
        }

        const float4* xp = (const float4*)(x + (size_t)s * 8);
        float4 x0 = xp[0], x1 = xp[1];
        float xv[8] = {x0.x, x0.y, x0.z, x0.w, x1.x, x1.y, x1.z, x1.w};

        f32x4 acc = {0.f, 0.f, 0.f, 0.f};
#pragma unroll
        for (int c = 0; c < 4; ++c) {
            bf16x8 afrag;
#pragma unroll
            for (int t = 0; t < 8; ++t) afrag[t] = (bf16)(he[c] * xv[t]);
            acc = __builtin_amdgcn_mfma_f32_16x16x32_bf16(afrag, bfrag[c], acc, 0, 0, 0);
        }
        {   // bias contraction (quad 0 active)
            bf16x8 a5 = {};
            if (q == 0)
#pragma unroll
                for (int t = 0; t < 8; ++t) a5[t] = (bf16)xv[t];
            acc = __builtin_amdgcn_mfma_f32_16x16x32_bf16(a5, bfrag5, acc, 0, 0, 0);
        }

        // Segment epilogue: rows sorted by dst; run-length combine, atomic
        // once per run. All quads compute identical scans; quad 0 commits.
        int   run_d   = __shfl(d, 0, 64);
        float run_sum = 0.f;
#pragma unroll
        for (int r = 0; r < 16; ++r) {
            int   dr = __shfl(d, r, 64);                       // wave-uniform
            float vr = __shfl(acc[r & 3], ((r >> 2) << 4) + m, 64);
            if (dr != run_d) {
                if (q == 0) atomicAdd(&agg[(size_t)run_d * 16 + m], run_sum);
                run_sum = 0.f; run_d = dr;
            }
            run_sum += vr;
        }
        if (q == 0) atomicAdd(&agg[(size_t)run_d * 16 + m], run_sum);
    }
}

// Finalize layer 1 + r2 precompute (deg from histogram).
__global__ void node_fin1(const float* __restrict__ agg, const int* __restrict__ deg,
                          const float* __restrict__ r1,
                          const float* __restrict__ root2,
                          const float* __restrict__ bias2,
                          float* __restrict__ h1, float* __restrict__ r2, int N)
{
    int t = blockIdx.x * blockDim.x + threadIdx.x;
    int v = t >> 4, o = t & 15;
    if (v >= N) return;
    float c = (float)deg[v]; c = c > 1.f ? c : 1.f;
    float h = agg[v * 16 + o] / c + r1[v * 16 + o];
    h = h > 0.f ? h : 0.f;
    h1[v * 16 + o] = h;
    float racc = 0.f;
#pragma unroll
    for (int i = 0; i < 16; ++i)
        racc += __shfl(h, i, 16) * root2[i * 16 + o];
    r2[v * 16 + o] = racc + bias2[o];
}

// Edge layer 2: K=256 via 8x mfma + 1 bias-mfma, segment epilogue.
__global__ void edge_l2(const float* __restrict__ h1g,
                        const float* __restrict__ ea_s,
                        const int*   __restrict__ src_s, const int* __restrict__ dst_s,
                        const float* __restrict__ W_e2a, const float* __restrict__ b_e2a,
                        const float* __restrict__ W_e2b, const float* __restrict__ b_e2b,
                        float* __restrict__ agg, int ntiles)
{
    const int lane = threadIdx.x & 63;
    const int m = lane & 15;
    const int q = lane >> 4;
    const int qh = q >> 1;            // j = 2c + qh
    const int ql = q & 1;             // i = ql*8 + t
    const int wave   = blockIdx.x * (blockDim.x >> 6) + (threadIdx.x >> 6);
    const int nwaves = gridDim.x * (blockDim.x >> 6);

    bf16x8 bfrag[8];
#pragma unroll
    for (int c = 0; c < 8; ++c) {
        int j = c * 2 + qh;
#pragma unroll
        for (int t = 0; t < 8; ++t)
            bfrag[c][t] = (bf16)W_e2b[((ql * 8 + t) * 16 + m) * 16 + j];
    }
    bf16x8 bfrag5 = {};
    if (q < 2)
#pragma unroll
        for (int t = 0; t < 8; ++t)
            bfrag5[t] = (bf16)b_e2b[(q * 8 + t) * 16 + m];

    for (int tile = wave; tile < ntiles; tile += nwaves) {
        int e = tile * 16 + m;
        int s = src_s[e];
        int d = dst_s[e];
        float t_ea = ea_s[e];

        float he[8];
#pragma unroll
        for (int c = 0; c < 8; ++c) {
            int j = c * 2 + qh;
            float h = W_e2a[j] * t_ea + b_e2a[j];
            he[c] = h > 0.f ? h : 0.f;
        }

        const float4* hp = (const float4*)(h1g + (size_t)s * 16 + ql * 8);
        float4 h0 = hp[0], h1v = hp[1];
        float hv[8] = {h0.x, h0.y, h0.z, h0.w, h1v.x, h1v.y, h1v.z, h1v.w};

        f32x4 acc = {0.f, 0.f, 0.f, 0.f};
#pragma unroll
        for (int c = 0; c < 8; ++c) {
            bf16x8 afrag;
#pragma unroll
            for (int t = 0; t < 8; ++t) afrag[t] = (bf16)(he[c] * hv[t]);
            acc = __builtin_amdgcn_mfma_f32_16x16x32_bf16(afrag, bfrag[c], acc, 0, 0, 0);
        }
        {   // bias contraction (quads 0,1 hold h1[s][0..16))
            bf16x8 a5 = {};
            if (q < 2)
#pragma unroll
                for (int t = 0; t < 8; ++t) a5[t] = (bf16)hv[t];
            acc = __builtin_amdgcn_mfma_f32_16x16x32_bf16(a5, bfrag5, acc, 0, 0, 0);
        }

        int   run_d   = __shfl(d, 0, 64);
        float run_sum = 0.f;
#pragma unroll
        for (int r = 0; r < 16; ++r) {
            int   dr = __shfl(d, r, 64);
            float vr = __shfl(acc[r & 3], ((r >> 2) << 4) + m, 64);
            if (dr != run_d) {
                if (q == 0) atomicAdd(&agg[(size_t)run_d * 16 + m], run_sum);
                run_sum = 0.f; run_d = dr;
            }
            run_sum += vr;
        }
        if (q == 0) atomicAdd(&agg[(size_t)run_d * 16 + m], run_sum);
    }
}

// Finalize layer 2: pure streaming elementwise.
__global__ void node_fin2(const float* __restrict__ agg, const int* __restrict__ deg,
                          const float* __restrict__ r2, const int* __restrict__ batch,
                          float* __restrict__ out_h, float* __restrict__ out_b, int N)
{
    int t = blockIdx.x * blockDim.x + threadIdx.x;
    int v = t >> 4, o = t & 15;
    if (v >= N) return;
    float c = (float)deg[v]; c = c > 1.f ? c : 1.f;
    float h = agg[v * 16 + o] / c + r2[v * 16 + o];
    h = h > 0.f ? h : 0.f;
    out_h[v * 16 + o] = h;
    if (o == 0) out_b[v] = (float)batch[v];
}

// Global mean pool: one block per graph, binary-search range, LDS reduce.
__global__ void pool_seg(const float* __restrict__ h, const int* __restrict__ batch,
                         float* __restrict__ out_g, int N)
{
    const int b = blockIdx.x;
    int lo = 0, hi = N;
    while (lo < hi) { int mid = (lo + hi) >> 1; if (batch[mid] < b) lo = mid + 1; else hi = mid; }
    const int start = lo;
    hi = N;
    while (lo < hi) { int mid = (lo + hi) >> 1; if (batch[mid] < b + 1) lo = mid + 1; else hi = mid; }
    const int end = lo;

    const int ch = threadIdx.x & 15, grp = threadIdx.x >> 4;
    float acc = 0.f;
    for (int v = start + grp; v < end; v += 16)
        acc += h[(size_t)v * 16 + ch];

    __shared__ float red[256];
    red[threadIdx.x] = acc;
    __syncthreads();
#pragma unroll
    for (int s = 128; s >= 16; s >>= 1) {
        if (threadIdx.x < s) red[threadIdx.x] += red[threadIdx.x + s];
        __syncthreads();
    }
    if (threadIdx.x < 16) {
        float c = (float)(end - start); c = c > 1.f ? c : 1.f;
        out_g[b * 16 + threadIdx.x] = red[threadIdx.x] / c;
    }
}

extern "C" void kernel_launch(void* const* d_in, const int* in_sizes, int n_in,
                              void* d_out, int out_size, void* d_ws, size_t ws_size,
                              hipStream_t stream)
{
    const float* x     = (const float*)d_in[0];
    const float* ea    = (const float*)d_in[1];
    const float* W_e1a = (const float*)d_in[2];
    const float* b_e1a = (const float*)d_in[3];
    const float* W_e1b = (const float*)d_in[4];
    const float* b_e1b = (const float*)d_in[5];
    const float* root1 = (const float*)d_in[6];
    const float* bias1 = (const float*)d_in[7];
    const float* W_e2a = (const float*)d_in[8];
    const float* b_e2a = (const float*)d_in[9];
    const float* W_e2b = (const float*)d_in[10];
    const float* b_e2b = (const float*)d_in[11];
    const float* root2 = (const float*)d_in[12];
    const float* bias2 = (const float*)d_in[13];
    const int*   eidx  = (const int*)d_in[14];
    const int*   batch = (const int*)d_in[15];

    const int E  = in_sizes[1];       // 800000
    const int N  = in_sizes[15];      // 50000
    const int Bg = (out_size - N * 16 - N) / 16;   // 64

    char* ws = (char*)d_ws;
    size_t off = 0;
    int*   deg  = (int*)(ws + off);   off += (size_t)N * 4;
    float* agg1 = (float*)(ws + off); off += (size_t)N * 16 * 4;
    float* agg2 = (float*)(ws + off); off += (size_t)N * 16 * 4;
    size_t zero_bytes = off;
    int*   bsum   = (int*)(ws + off); off += 1024 * 4;
    int*   cursor = (int*)(ws + off); off += (size_t)N * 4;
    int*   src_s  = (int*)(ws + off); off += (size_t)E * 4;
    int*   dst_s  = (int*)(ws + off); off += (size_t)E * 4;
    float* ea_s   = (float*)(ws + off); off += (size_t)E * 4;
    float* h1 = (float*)(ws + off); off += (size_t)N * 16 * 4;
    float* r1 = (float*)(ws + off); off += (size_t)N * 16 * 4;
    float* r2 = (float*)(ws + off); off += (size_t)N * 16 * 4;

    hipMemsetAsync(d_ws, 0, zero_bytes, stream);

    int nodeBlocks = (N * 16 + 255) / 256;
    int edgeBlocks = (E + 255) / 256;
    int scanBlocks = (N + 1023) / 1024;
    int ntiles = E / 16;

    hist_deg<<<edgeBlocks, 256, 0, stream>>>(eidx, deg, E);
    partial_sums<<<scanBlocks, 256, 0, stream>>>(deg, bsum, N);
    scan_bsum<<<1, 64, 0, stream>>>(bsum, scanBlocks);
    emit_cursor<<<scanBlocks, 256, 0, stream>>>(deg, bsum, cursor, N);
    scatter_edges<<<edgeBlocks, 256, 0, stream>>>(eidx, ea, cursor,
                                                  src_s, dst_s, ea_s, E);

    node_pre1<<<nodeBlocks, 256, 0, stream>>>(x, root1, bias1, r1, N);
    edge_l1<<<2048, 256, 0, stream>>>(x, ea_s, src_s, dst_s,
                                      W_e1a, b_e1a, W_e1b, b_e1b, agg1, ntiles);
    node_fin1<<<nodeBlocks, 256, 0, stream>>>(agg1, deg, r1, root2, bias2,
                                              h1, r2, N);
    edge_l2<<<2048, 256, 0, stream>>>(h1, ea_s, src_s, dst_s,
                                      W_e2a, b_e2a, W_e2b, b_e2b, agg2, ntiles);

    float* out_h = (float*)d_out;
    float* out_g = out_h + (size_t)N * 16;
    float* out_b = out_g + (size_t)Bg * 16;
    node_fin2<<<nodeBlocks, 256, 0, stream>>>(agg2, deg, r2, batch, out_h,
                                              out_b, N);
    pool_seg<<<Bg, 256, 0, stream>>>(out_h, batch, out_g, N);
}

// Round 6
// 329.404 us; speedup vs baseline: 1.2123x; 1.0582x over previous
//
#include <hip/hip_runtime.h>
#include <hip/hip_bf16.h>

typedef __bf16 bf16;
typedef __bf16 bf16x8 __attribute__((ext_vector_type(8)));
typedef float  f32x4  __attribute__((ext_vector_type(4)));

// ---------------------------------------------------------------------------
// NNConv via shared-weight GEMM on rank-1 edge features:
//   msg[e] = Z[e] @ W' (+ bias fold),  Z[e][(j,i)] = he[e][j]*x[src][i]
// Edges counting-sorted by dst in-call (hist -> multi-block scan -> scatter).
// R6: edge epilogue = lane-local run combine (lane (q,m) owns C rows 4q..4q+3
//     for col m -- NO value shuffles), <=4 predicated atomics per lane.
//     2-way tile ILP per wave iteration.
// Pooling: batch sorted -> per-graph block segment reduction, no atomics.
// ---------------------------------------------------------------------------

__global__ void hist_deg(const int* __restrict__ eidx, int* __restrict__ deg, int E)
{
    int e = blockIdx.x * blockDim.x + threadIdx.x;
    if (e < E) atomicAdd(&deg[eidx[E + e]], 1);
}

__global__ void partial_sums(const int* __restrict__ deg, int* __restrict__ bsum, int N)
{
    __shared__ int ts[256];
    const int t = threadIdx.x;
    const int base = blockIdx.x * 1024 + t * 4;
    int s = 0;
#pragma unroll
    for (int k = 0; k < 4; ++k)
        if (base + k < N) s += deg[base + k];
    ts[t] = s;
    __syncthreads();
    for (int st = 128; st >= 1; st >>= 1) {
        if (t < st) ts[t] += ts[t + st];
        __syncthreads();
    }
    if (t == 0) bsum[blockIdx.x] = ts[0];
}

__global__ void scan_bsum(int* __restrict__ bsum, int nb)
{
    const int lane = threadIdx.x;   // 64 threads
    int base = 0;
    for (int start = 0; start < nb; start += 64) {
        int i = start + lane;
        int orig = (i < nb) ? bsum[i] : 0;
        int v = orig;
        for (int off = 1; off < 64; off <<= 1) {
            int u = __shfl_up(v, off, 64);
            if (lane >= off) v += u;
        }
        if (i < nb) bsum[i] = base + v - orig;   // exclusive
        base += __shfl(v, 63, 64);
    }
}

__global__ void emit_cursor(const int* __restrict__ deg, const int* __restrict__ bsum,
                            int* __restrict__ cursor, int N)
{
    __shared__ int ts[256];
    const int t = threadIdx.x;
    const int base = blockIdx.x * 1024 + t * 4;
    int v[4];
#pragma unroll
    for (int k = 0; k < 4; ++k)
        v[k] = (base + k < N) ? deg[base + k] : 0;
    int s = v[0] + v[1] + v[2] + v[3];
    ts[t] = s;
    __syncthreads();
    for (int off = 1; off < 256; off <<= 1) {
        int add = (t >= off) ? ts[t - off] : 0;
        __syncthreads();
        ts[t] += add;
        __syncthreads();
    }
    int excl = ts[t] - s + bsum[blockIdx.x];
    if (base + 0 < N) cursor[base + 0] = excl;
    if (base + 1 < N) cursor[base + 1] = excl + v[0];
    if (base + 2 < N) cursor[base + 2] = excl + v[0] + v[1];
    if (base + 3 < N) cursor[base + 3] = excl + v[0] + v[1] + v[2];
}

__global__ void scatter_edges(const int* __restrict__ eidx, const float* __restrict__ ea,
                              int* __restrict__ cursor,
                              int* __restrict__ src_s, int* __restrict__ dst_s,
                              float* __restrict__ ea_s, int E)
{
    int e = blockIdx.x * blockDim.x + threadIdx.x;
    if (e >= E) return;
    int d = eidx[E + e];
    int p = atomicAdd(&cursor[d], 1);
    src_s[p] = eidx[e];
    dst_s[p] = d;
    ea_s[p]  = ea[e];
}

__global__ void node_pre1(const float* __restrict__ x,
                          const float* __restrict__ root1,
                          const float* __restrict__ bias1,
                          float* __restrict__ r1, int N)
{
    int t = blockIdx.x * blockDim.x + threadIdx.x;
    int v = t >> 4, o = t & 15;
    if (v >= N) return;
    float racc = 0.f;
#pragma unroll
    for (int i = 0; i < 8; ++i)
        racc += x[v * 8 + i] * root1[i * 16 + o];
    r1[v * 16 + o] = racc + bias1[o];
}

// Lane-local sorted-run commit: lane owns rows 4q..4q+3 (col m) in acc[0..3].
__device__ __forceinline__ void commit_runs(const f32x4& acc, const int* rd,
                                            float* __restrict__ agg, int m)
{
    float run = acc[0];
    int   cur = rd[0];
#pragma unroll
    for (int k = 1; k < 4; ++k) {
        if (rd[k] == cur) run += acc[k];
        else {
            atomicAdd(&agg[(size_t)cur * 16 + m], run);
            cur = rd[k]; run = acc[k];
        }
    }
    atomicAdd(&agg[(size_t)cur * 16 + m], run);
}

// Edge layer 1: sorted tiles, K=128 via 4x mfma + 1 bias-mfma. 2-way ILP.
__global__ void edge_l1(const float* __restrict__ x,
                        const float* __restrict__ ea_s,
                        const int*   __restrict__ src_s, const int* __restrict__ dst_s,
                        const float* __restrict__ W_e1a, const float* __restrict__ b_e1a,
                        const float* __restrict__ W_e1b, const float* __restrict__ b_e1b,
                        float* __restrict__ agg, int ntiles)
{
    const int lane = threadIdx.x & 63;
    const int m = lane & 15;          // A row (edge) / B,C col (chan)
    const int q = lane >> 4;
    const int wave   = blockIdx.x * (blockDim.x >> 6) + (threadIdx.x >> 6);
    const int nwaves = gridDim.x * (blockDim.x >> 6);

    bf16x8 bfrag[4];
#pragma unroll
    for (int c = 0; c < 4; ++c)
#pragma unroll
        for (int t = 0; t < 8; ++t)
            bfrag[c][t] = (bf16)W_e1b[(t * 16 + m) * 16 + (c * 4 + q)];
    bf16x8 bfrag5 = {};
    if (q == 0)
#pragma unroll
        for (int t = 0; t < 8; ++t)
            bfrag5[t] = (bf16)b_e1b[t * 16 + m];

    const float wa[4] = { W_e1a[q], W_e1a[4 + q], W_e1a[8 + q], W_e1a[12 + q] };
    const float ba[4] = { b_e1a[q], b_e1a[4 + q], b_e1a[8 + q], b_e1a[12 + q] };

    for (int base = wave * 2; base < ntiles; base += nwaves * 2) {
#pragma unroll
        for (int u = 0; u < 2; ++u) {
            int tile = base + u;
            if (tile >= ntiles) break;
            int e = tile * 16 + m;
            int s = src_s[e];
            int d = dst_s[e];
            float t_ea = ea_s[e];

            float he[4];
#pragma unroll
            for (int c = 0; c < 4; ++c) {
                float h = wa[c] * t_ea + ba[c];
                he[c] = h > 0.f ? h : 0.f;
            }

            const float4* xp = (const float4*)(x + (size_t)s * 8);
            float4 x0 = xp[0], x1 = xp[1];
            float xv[8] = {x0.x, x0.y, x0.z, x0.w, x1.x, x1.y, x1.z, x1.w};

            f32x4 acc = {0.f, 0.f, 0.f, 0.f};
#pragma unroll
            for (int c = 0; c < 4; ++c) {
                bf16x8 afrag;
#pragma unroll
                for (int t = 0; t < 8; ++t) afrag[t] = (bf16)(he[c] * xv[t]);
                acc = __builtin_amdgcn_mfma_f32_16x16x32_bf16(afrag, bfrag[c], acc, 0, 0, 0);
            }
            {   // bias contraction (quad 0 active)
                bf16x8 a5 = {};
                if (q == 0)
#pragma unroll
                    for (int t = 0; t < 8; ++t) a5[t] = (bf16)xv[t];
                acc = __builtin_amdgcn_mfma_f32_16x16x32_bf16(a5, bfrag5, acc, 0, 0, 0);
            }

            int rd[4];
#pragma unroll
            for (int k = 0; k < 4; ++k) rd[k] = __shfl(d, 4 * q + k, 64);
            commit_runs(acc, rd, agg, m);
        }
    }
}

// Finalize layer 1 + r2 precompute (deg from histogram).
__global__ void node_fin1(const float* __restrict__ agg, const int* __restrict__ deg,
                          const float* __restrict__ r1,
                          const float* __restrict__ root2,
                          const float* __restrict__ bias2,
                          float* __restrict__ h1, float* __restrict__ r2, int N)
{
    int t = blockIdx.x * blockDim.x + threadIdx.x;
    int v = t >> 4, o = t & 15;
    if (v >= N) return;
    float c = (float)deg[v]; c = c > 1.f ? c : 1.f;
    float h = agg[v * 16 + o] / c + r1[v * 16 + o];
    h = h > 0.f ? h : 0.f;
    h1[v * 16 + o] = h;
    float racc = 0.f;
#pragma unroll
    for (int i = 0; i < 16; ++i)
        racc += __shfl(h, i, 16) * root2[i * 16 + o];
    r2[v * 16 + o] = racc + bias2[o];
}

// Edge layer 2: K=256 via 8x mfma + 1 bias-mfma. 2-way ILP.
__global__ void edge_l2(const float* __restrict__ h1g,
                        const float* __restrict__ ea_s,
                        const int*   __restrict__ src_s, const int* __restrict__ dst_s,
                        const float* __restrict__ W_e2a, const float* __restrict__ b_e2a,
                        const float* __restrict__ W_e2b, const float* __restrict__ b_e2b,
                        float* __restrict__ agg, int ntiles)
{
    const int lane = threadIdx.x & 63;
    const int m = lane & 15;
    const int q = lane >> 4;
    const int qh = q >> 1;            // j = 2c + qh
    const int ql = q & 1;             // i = ql*8 + t
    const int wave   = blockIdx.x * (blockDim.x >> 6) + (threadIdx.x >> 6);
    const int nwaves = gridDim.x * (blockDim.x >> 6);

    bf16x8 bfrag[8];
#pragma unroll
    for (int c = 0; c < 8; ++c) {
        int j = c * 2 + qh;
#pragma unroll
        for (int t = 0; t < 8; ++t)
            bfrag[c][t] = (bf16)W_e2b[((ql * 8 + t) * 16 + m) * 16 + j];
    }
    bf16x8 bfrag5 = {};
    if (q < 2)
#pragma unroll
        for (int t = 0; t < 8; ++t)
            bfrag5[t] = (bf16)b_e2b[(q * 8 + t) * 16 + m];

    float wa[8], ba[8];
#pragma unroll
    for (int c = 0; c < 8; ++c) {
        wa[c] = W_e2a[c * 2 + qh];
        ba[c] = b_e2a[c * 2 + qh];
    }

    for (int base = wave * 2; base < ntiles; base += nwaves * 2) {
#pragma unroll
        for (int u = 0; u < 2; ++u) {
            int tile = base + u;
            if (tile >= ntiles) break;
            int e = tile * 16 + m;
            int s = src_s[e];
            int d = dst_s[e];
            float t_ea = ea_s[e];

            float he[8];
#pragma unroll
            for (int c = 0; c < 8; ++c) {
                float h = wa[c] * t_ea + ba[c];
                he[c] = h > 0.f ? h : 0.f;
            }

            const float4* hp = (const float4*)(h1g + (size_t)s * 16 + ql * 8);
            float4 h0 = hp[0], h1v = hp[1];
            float hv[8] = {h0.x, h0.y, h0.z, h0.w, h1v.x, h1v.y, h1v.z, h1v.w};

            f32x4 acc = {0.f, 0.f, 0.f, 0.f};
#pragma unroll
            for (int c = 0; c < 8; ++c) {
                bf16x8 afrag;
#pragma unroll
                for (int t = 0; t < 8; ++t) afrag[t] = (bf16)(he[c] * hv[t]);
                acc = __builtin_amdgcn_mfma_f32_16x16x32_bf16(afrag, bfrag[c], acc, 0, 0, 0);
            }
            {   // bias contraction (quads 0,1 hold h1[s][0..16))
                bf16x8 a5 = {};
                if (q < 2)
#pragma unroll
                    for (int t = 0; t < 8; ++t) a5[t] = (bf16)hv[t];
                acc = __builtin_amdgcn_mfma_f32_16x16x32_bf16(a5, bfrag5, acc, 0, 0, 0);
            }

            int rd[4];
#pragma unroll
            for (int k = 0; k < 4; ++k) rd[k] = __shfl(d, 4 * q + k, 64);
            commit_runs(acc, rd, agg, m);
        }
    }
}

// Finalize layer 2: pure streaming elementwise.
__global__ void node_fin2(const float* __restrict__ agg, const int* __restrict__ deg,
                          const float* __restrict__ r2, const int* __restrict__ batch,
                          float* __restrict__ out_h, float* __restrict__ out_b, int N)
{
    int t = blockIdx.x * blockDim.x + threadIdx.x;
    int v = t >> 4, o = t & 15;
    if (v >= N) return;
    float c = (float)deg[v]; c = c > 1.f ? c : 1.f;
    float h = agg[v * 16 + o] / c + r2[v * 16 + o];
    h = h > 0.f ? h : 0.f;
    out_h[v * 16 + o] = h;
    if (o == 0) out_b[v] = (float)batch[v];
}

// Global mean pool: one block per graph, binary-search range, LDS reduce.
__global__ void pool_seg(const float* __restrict__ h, const int* __restrict__ batch,
                         float* __restrict__ out_g, int N)
{
    const int b = blockIdx.x;
    int lo = 0, hi = N;
    while (lo < hi) { int mid = (lo + hi) >> 1; if (batch[mid] < b) lo = mid + 1; else hi = mid; }
    const int start = lo;
    hi = N;
    while (lo < hi) { int mid = (lo + hi) >> 1; if (batch[mid] < b + 1) lo = mid + 1; else hi = mid; }
    const int end = lo;

    const int ch = threadIdx.x & 15, grp = threadIdx.x >> 4;
    float acc = 0.f;
    for (int v = start + grp; v < end; v += 16)
        acc += h[(size_t)v * 16 + ch];

    __shared__ float red[256];
    red[threadIdx.x] = acc;
    __syncthreads();
#pragma unroll
    for (int s = 128; s >= 16; s >>= 1) {
        if (threadIdx.x < s) red[threadIdx.x] += red[threadIdx.x + s];
        __syncthreads();
    }
    if (threadIdx.x < 16) {
        float c = (float)(end - start); c = c > 1.f ? c : 1.f;
        out_g[b * 16 + threadIdx.x] = red[threadIdx.x] / c;
    }
}

extern "C" void kernel_launch(void* const* d_in, const int* in_sizes, int n_in,
                              void* d_out, int out_size, void* d_ws, size_t ws_size,
                              hipStream_t stream)
{
    const float* x     = (const float*)d_in[0];
    const float* ea    = (const float*)d_in[1];
    const float* W_e1a = (const float*)d_in[2];
    const float* b_e1a = (const float*)d_in[3];
    const float* W_e1b = (const float*)d_in[4];
    const float* b_e1b = (const float*)d_in[5];
    const float* root1 = (const float*)d_in[6];
    const float* bias1 = (const float*)d_in[7];
    const float* W_e2a = (const float*)d_in[8];
    const float* b_e2a = (const float*)d_in[9];
    const float* W_e2b = (const float*)d_in[10];
    const float* b_e2b = (const float*)d_in[11];
    const float* root2 = (const float*)d_in[12];
    const float* bias2 = (const float*)d_in[13];
    const int*   eidx  = (const int*)d_in[14];
    const int*   batch = (const int*)d_in[15];

    const int E  = in_sizes[1];       // 800000
    const int N  = in_sizes[15];      // 50000
    const int Bg = (out_size - N * 16 - N) / 16;   // 64

    char* ws = (char*)d_ws;
    size_t off = 0;
    int*   deg  = (int*)(ws + off);   off += (size_t)N * 4;
    float* agg1 = (float*)(ws + off); off += (size_t)N * 16 * 4;
    float* agg2 = (float*)(ws + off); off += (size_t)N * 16 * 4;
    size_t zero_bytes = off;
    int*   bsum   = (int*)(ws + off); off += 1024 * 4;
    int*   cursor = (int*)(ws + off); off += (size_t)N * 4;
    int*   src_s  = (int*)(ws + off); off += (size_t)E * 4;
    int*   dst_s  = (int*)(ws + off); off += (size_t)E * 4;
    float* ea_s   = (float*)(ws + off); off += (size_t)E * 4;
    float* h1 = (float*)(ws + off); off += (size_t)N * 16 * 4;
    float* r1 = (float*)(ws + off); off += (size_t)N * 16 * 4;
    float* r2 = (float*)(ws + off); off += (size_t)N * 16 * 4;

    hipMemsetAsync(d_ws, 0, zero_bytes, stream);

    int nodeBlocks = (N * 16 + 255) / 256;
    int edgeBlocks = (E + 255) / 256;
    int scanBlocks = (N + 1023) / 1024;
    int ntiles = E / 16;

    hist_deg<<<edgeBlocks, 256, 0, stream>>>(eidx, deg, E);
    partial_sums<<<scanBlocks, 256, 0, stream>>>(deg, bsum, N);
    scan_bsum<<<1, 64, 0, stream>>>(bsum, scanBlocks);
    emit_cursor<<<scanBlocks, 256, 0, stream>>>(deg, bsum, cursor, N);
    scatter_edges<<<edgeBlocks, 256, 0, stream>>>(eidx, ea, cursor,
                                                  src_s, dst_s, ea_s, E);

    node_pre1<<<nodeBlocks, 256, 0, stream>>>(x, root1, bias1, r1, N);
    edge_l1<<<1280, 256, 0, stream>>>(x, ea_s, src_s, dst_s,
                                      W_e1a, b_e1a, W_e1b, b_e1b, agg1, ntiles);
    node_fin1<<<nodeBlocks, 256, 0, stream>>>(agg1, deg, r1, root2, bias2,
                                              h1, r2, N);
    edge_l2<<<1280, 256, 0, stream>>>(h1, ea_s, src_s, dst_s,
                                      W_e2a, b_e2a, W_e2b, b_e2b, agg2, ntiles);

    float* out_h = (float*)d_out;
    float* out_g = out_h + (size_t)N * 16;
    float* out_b = out_g + (size_t)Bg * 16;
    node_fin2<<<nodeBlocks, 256, 0, stream>>>(agg2, deg, r2, batch, out_h,
                                              out_b, N);
    pool_seg<<<Bg, 256, 0, stream>>>(out_h, batch, out_g, N);
}